// Round 2
// baseline (384.157 us; speedup 1.0000x reference)
//
#include <hip/hip_runtime.h>

// Problem constants (fixed by the reference)
constexpr int B = 2, H = 8, N = 64, T = 32, D = 32;
constexpr int TD = T * D;                 // 1024
constexpr float INV_SCALE = 1.0f / 32.0f; // 1/sqrt(T*D); TAU = 1

// One block per (b,h,i): grid = B*H*N = 1024 blocks, 256 threads = 4 waves.
__global__ __launch_bounds__(256, 4) void mha_kernel(
    const float* __restrict__ Q,
    const float* __restrict__ K,
    const float* __restrict__ V,
    const int* __restrict__ mask,
    float* __restrict__ out)
{
    const int bid  = blockIdx.x;
    const int i    = bid & (N - 1);
    const int bh   = bid >> 6;            // 0..15
    const int tid  = threadIdx.x;
    const int wave = tid >> 6;
    const int lane = tid & 63;

    __shared__ float s_qk[N];
    __shared__ float s_attn[N];

    // ---------- Phase 1: qk[j] = dot(Q[bh,i,:], K[bh,j,:]) * INV_SCALE ----------
    // Each lane covers 16 elements: 4 float4 segments at +0/+256/+512/+768.
    const float* qrow = Q + (size_t)(bh * N + i) * TD;
    const float4 q0 = *(const float4*)(qrow + 4 * lane);
    const float4 q1 = *(const float4*)(qrow + 4 * lane + 256);
    const float4 q2 = *(const float4*)(qrow + 4 * lane + 512);
    const float4 q3 = *(const float4*)(qrow + 4 * lane + 768);

    for (int jj = 0; jj < 16; ++jj) {
        const int j = wave * 16 + jj;     // each wave computes 16 of the 64 dots
        const float* krow = K + (size_t)(bh * N + j) * TD;
        const float4 k0 = *(const float4*)(krow + 4 * lane);
        const float4 k1 = *(const float4*)(krow + 4 * lane + 256);
        const float4 k2 = *(const float4*)(krow + 4 * lane + 512);
        const float4 k3 = *(const float4*)(krow + 4 * lane + 768);
        float p = q0.x * k0.x + q0.y * k0.y + q0.z * k0.z + q0.w * k0.w
                + q1.x * k1.x + q1.y * k1.y + q1.z * k1.z + q1.w * k1.w
                + q2.x * k2.x + q2.y * k2.y + q2.z * k2.z + q2.w * k2.w
                + q3.x * k3.x + q3.y * k3.y + q3.z * k3.z + q3.w * k3.w;
        // 64-lane tree reduction
        #pragma unroll
        for (int off = 32; off > 0; off >>= 1)
            p += __shfl_down(p, off, 64);
        if (lane == 0) {
            const int m = mask[(bh * N + i) * N + j];
            s_qk[j] = (m == 0) ? -INFINITY : p * INV_SCALE;
        }
    }
    __syncthreads();

    // ---------- Softmax over j (redundant per thread; LDS broadcast reads) ----------
    float mx = -INFINITY;
    #pragma unroll
    for (int j = 0; j < N; ++j) mx = fmaxf(mx, s_qk[j]);
    float sum = 0.f;
    #pragma unroll
    for (int j = 0; j < N; ++j) sum += __expf(s_qk[j] - mx);
    const float inv = 1.0f / sum;
    if (tid < N) s_attn[tid] = __expf(s_qk[tid] - mx) * inv;
    __syncthreads();

    // ---------- Phase 2: out[tf] = sum_j attn[j] * V[bh, j, i, tf] ----------
    // 256 threads x float4 = 1024 outputs: thread owns elements 4*tid..4*tid+3.
    // V row for (j): contiguous 1024 floats at ((bh*N + j)*N + i)*TD.
    float4 acc = make_float4(0.f, 0.f, 0.f, 0.f);
    const float* vbase = V + ((size_t)(bh * N) * N + i) * TD + tid * 4;
    const size_t jstride = (size_t)N * TD;   // 65536 floats between consecutive j

    #pragma unroll 8
    for (int j = 0; j < N; ++j) {
        const float a = s_attn[j];
        const float4 v = *(const float4*)(vbase + (size_t)j * jstride);
        acc.x += a * v.x;
        acc.y += a * v.y;
        acc.z += a * v.z;
        acc.w += a * v.w;
    }

    *(float4*)(out + (size_t)(bh * N + i) * TD + tid * 4) = acc;
}

extern "C" void kernel_launch(void* const* d_in, const int* in_sizes, int n_in,
                              void* d_out, int out_size, void* d_ws, size_t ws_size,
                              hipStream_t stream) {
    const float* Q    = (const float*)d_in[0];
    const float* K    = (const float*)d_in[1];
    const float* V    = (const float*)d_in[2];
    const int*   mask = (const int*)d_in[3];
    float*       out  = (float*)d_out;

    mha_kernel<<<dim3(B * H * N), dim3(256), 0, stream>>>(Q, K, V, mask, out);
}

// Round 4
// 360.191 us; speedup vs baseline: 1.0665x; 1.0665x over previous
//
#include <hip/hip_runtime.h>

// Problem constants (fixed by the reference)
constexpr int B = 2, H = 8, N = 64, T = 32, D = 32;
constexpr int TD = T * D;                 // 1024
constexpr float INV_SCALE = 1.0f / 32.0f; // 1/sqrt(T*D); TAU = 1

// Native clang vector type — required by __builtin_nontemporal_load/store
// (HIP_vector_type float4 is a struct and is rejected).
typedef float vfloat4 __attribute__((ext_vector_type(4)));

// One block per (b,h,i): grid = B*H*N = 1024 blocks, 256 threads = 4 waves.
// launch_bounds (256,4): 4 blocks/CU -> all 1024 blocks co-resident on 256 CUs.
__global__ __launch_bounds__(256, 4) void mha_kernel(
    const float* __restrict__ Q,
    const float* __restrict__ K,
    const float* __restrict__ V,
    const int* __restrict__ mask,
    float* __restrict__ out)
{
    const int bid  = blockIdx.x;
    const int i    = bid & (N - 1);
    const int bh   = bid >> 6;            // 0..15
    const int tid  = threadIdx.x;
    const int wave = tid >> 6;
    const int lane = tid & 63;

    __shared__ float s_qk[N];

    // ---------- Phase 1: qk[j] = dot(Q[bh,i,:], K[bh,j,:]) * INV_SCALE ----------
    // Each lane covers 16 elements: 4 float4 segments at +0/+256/+512/+768.
    const float* qrow = Q + (size_t)(bh * N + i) * TD;
    const float4 q0 = *(const float4*)(qrow + 4 * lane);
    const float4 q1 = *(const float4*)(qrow + 4 * lane + 256);
    const float4 q2 = *(const float4*)(qrow + 4 * lane + 512);
    const float4 q3 = *(const float4*)(qrow + 4 * lane + 768);

    #pragma unroll 2
    for (int jj = 0; jj < 16; ++jj) {
        const int j = wave * 16 + jj;     // each wave computes 16 of the 64 dots
        const float* krow = K + (size_t)(bh * N + j) * TD;
        const float4 k0 = *(const float4*)(krow + 4 * lane);
        const float4 k1 = *(const float4*)(krow + 4 * lane + 256);
        const float4 k2 = *(const float4*)(krow + 4 * lane + 512);
        const float4 k3 = *(const float4*)(krow + 4 * lane + 768);
        float p = q0.x * k0.x + q0.y * k0.y + q0.z * k0.z + q0.w * k0.w
                + q1.x * k1.x + q1.y * k1.y + q1.z * k1.z + q1.w * k1.w
                + q2.x * k2.x + q2.y * k2.y + q2.z * k2.z + q2.w * k2.w
                + q3.x * k3.x + q3.y * k3.y + q3.z * k3.z + q3.w * k3.w;
        // 64-lane tree reduction
        #pragma unroll
        for (int off = 32; off > 0; off >>= 1)
            p += __shfl_down(p, off, 64);
        if (lane == 0) {
            const int m = mask[(bh * N + i) * N + j];
            s_qk[j] = (m == 0) ? -INFINITY : p * INV_SCALE;
        }
    }
    __syncthreads();

    // ---------- Softmax max (redundant per thread; LDS broadcast reads) ----------
    float mx = -INFINITY;
    #pragma unroll
    for (int j = 0; j < N; ++j) mx = fmaxf(mx, s_qk[j]);

    // ---------- Phase 2 (fused): acc = sum_j exp(qk_j - mx) * V[bh,j,i,tf]; out = acc/sum ----------
    // 256 threads x float4 = 1024 outputs: thread owns elements 4*tid..4*tid+3.
    // V is streamed non-temporally (zero reuse) to keep K/Q resident in L2.
    vfloat4 acc = {0.f, 0.f, 0.f, 0.f};
    float sum = 0.f;
    const vfloat4* vptr = (const vfloat4*)(V + ((size_t)(bh * N) * N + i) * TD) + tid;
    const size_t jstride4 = (size_t)N * TD / 4;   // vfloat4 stride between consecutive j

    #pragma unroll 8
    for (int j = 0; j < N; ++j) {
        const float w = __expf(s_qk[j] - mx);     // exp(-inf)=0 handles masked j
        sum += w;
        const vfloat4 v = __builtin_nontemporal_load(vptr + (size_t)j * jstride4);
        acc += w * v;
    }

    acc *= (1.0f / sum);
    __builtin_nontemporal_store(acc, (vfloat4*)(out + (size_t)(bh * N + i) * TD) + tid);
}

extern "C" void kernel_launch(void* const* d_in, const int* in_sizes, int n_in,
                              void* d_out, int out_size, void* d_ws, size_t ws_size,
                              hipStream_t stream) {
    const float* Q    = (const float*)d_in[0];
    const float* K    = (const float*)d_in[1];
    const float* V    = (const float*)d_in[2];
    const int*   mask = (const int*)d_in[3];
    float*       out  = (float*)d_out;

    mha_kernel<<<dim3(B * H * N), dim3(256), 0, stream>>>(Q, K, V, mask, out);
}

// Round 5
// 357.448 us; speedup vs baseline: 1.0747x; 1.0077x over previous
//
#include <hip/hip_runtime.h>

// Problem constants (fixed by the reference)
constexpr int B = 2, H = 8, N = 64, T = 32, D = 32;
constexpr int TD = T * D;                 // 1024
constexpr float INV_SCALE = 1.0f / 32.0f; // 1/sqrt(T*D); TAU = 1

// Native clang vector type — required by __builtin_nontemporal_load/store
// (HIP_vector_type float4 is a struct and is rejected).
typedef float vfloat4 __attribute__((ext_vector_type(4)));

constexpr int PF = 8;                     // V rows prefetched across the barrier

// One block per (b,h,i): grid = B*H*N = 1024 blocks, 256 threads = 4 waves.
// launch_bounds (256,4): 4 blocks/CU -> all 1024 blocks co-resident on 256 CUs.
__global__ __launch_bounds__(256, 4) void mha_kernel(
    const float* __restrict__ Q,
    const float* __restrict__ K,
    const float* __restrict__ V,
    const int* __restrict__ mask,
    float* __restrict__ out)
{
    const int bid  = blockIdx.x;
    const int i    = bid & (N - 1);
    const int bh   = bid >> 6;            // 0..15
    const int tid  = threadIdx.x;
    const int wave = tid >> 6;
    const int lane = tid & 63;

    __shared__ float s_qk[N];

    // ---------- V prefetch: first PF rows issued BEFORE phase 1 ----------
    // The vmcnt(0) drain at __syncthreads() completes these during the K-dot
    // phase, overlapping ~PF/64 of the V stream with phase 1.
    const vfloat4* vptr = (const vfloat4*)(V + ((size_t)(bh * N) * N + i) * TD) + tid;
    const size_t jstride4 = (size_t)N * TD / 4;   // vfloat4 stride between consecutive j
    vfloat4 pre[PF];
    #pragma unroll
    for (int j = 0; j < PF; ++j)
        pre[j] = __builtin_nontemporal_load(vptr + (size_t)j * jstride4);

    // ---------- Phase 1: qk[j] = dot(Q[bh,i,:], K[bh,j,:]) * INV_SCALE ----------
    // Each lane covers 16 elements: 4 float4 segments at +0/+256/+512/+768.
    const float* qrow = Q + (size_t)(bh * N + i) * TD;
    const float4 q0 = *(const float4*)(qrow + 4 * lane);
    const float4 q1 = *(const float4*)(qrow + 4 * lane + 256);
    const float4 q2 = *(const float4*)(qrow + 4 * lane + 512);
    const float4 q3 = *(const float4*)(qrow + 4 * lane + 768);

    #pragma unroll 2
    for (int jj = 0; jj < 16; ++jj) {
        const int j = wave * 16 + jj;     // each wave computes 16 of the 64 dots
        const float* krow = K + (size_t)(bh * N + j) * TD;
        const float4 k0 = *(const float4*)(krow + 4 * lane);
        const float4 k1 = *(const float4*)(krow + 4 * lane + 256);
        const float4 k2 = *(const float4*)(krow + 4 * lane + 512);
        const float4 k3 = *(const float4*)(krow + 4 * lane + 768);
        float p = q0.x * k0.x + q0.y * k0.y + q0.z * k0.z + q0.w * k0.w
                + q1.x * k1.x + q1.y * k1.y + q1.z * k1.z + q1.w * k1.w
                + q2.x * k2.x + q2.y * k2.y + q2.z * k2.z + q2.w * k2.w
                + q3.x * k3.x + q3.y * k3.y + q3.z * k3.z + q3.w * k3.w;
        // 64-lane tree reduction
        #pragma unroll
        for (int off = 32; off > 0; off >>= 1)
            p += __shfl_down(p, off, 64);
        if (lane == 0) {
            const int m = mask[(bh * N + i) * N + j];
            s_qk[j] = (m == 0) ? -INFINITY : p * INV_SCALE;
        }
    }
    __syncthreads();

    // ---------- Softmax max (redundant per thread; LDS broadcast reads) ----------
    float mx = -INFINITY;
    #pragma unroll
    for (int j = 0; j < N; ++j) mx = fmaxf(mx, s_qk[j]);

    // ---------- Phase 2 (fused): acc = sum_j exp(qk_j - mx) * V[bh,j,i,tf]; out = acc/sum ----------
    // 256 threads x float4 = 1024 outputs: thread owns elements 4*tid..4*tid+3.
    // V is streamed non-temporally (zero reuse) to keep K/Q resident in L2.
    vfloat4 acc = {0.f, 0.f, 0.f, 0.f};
    float sum = 0.f;

    #pragma unroll
    for (int j = 0; j < PF; ++j) {        // prefetched rows
        const float w = __expf(s_qk[j] - mx);
        sum += w;
        acc += w * pre[j];
    }
    #pragma unroll 16
    for (int j = PF; j < N; ++j) {
        const float w = __expf(s_qk[j] - mx);     // exp(-inf)=0 handles masked j
        sum += w;
        const vfloat4 v = __builtin_nontemporal_load(vptr + (size_t)j * jstride4);
        acc += w * v;
    }

    acc *= (1.0f / sum);
    __builtin_nontemporal_store(acc, (vfloat4*)(out + (size_t)(bh * N + i) * TD) + tid);
}

extern "C" void kernel_launch(void* const* d_in, const int* in_sizes, int n_in,
                              void* d_out, int out_size, void* d_ws, size_t ws_size,
                              hipStream_t stream) {
    const float* Q    = (const float*)d_in[0];
    const float* K    = (const float*)d_in[1];
    const float* V    = (const float*)d_in[2];
    const int*   mask = (const int*)d_in[3];
    float*       out  = (float*)d_out;

    mha_kernel<<<dim3(B * H * N), dim3(256), 0, stream>>>(Q, K, V, mask, out);
}